// Round 4
// baseline (303.758 us; speedup 1.0000x reference)
//
#include <hip/hip_runtime.h>
#include <math.h>

// Problem: images [64,256,256] f32 -> patches [16384][256] f32 (identity perm)
//          tokens [16384] = argmin_v ||patch - vocab[v]||^2, vocab [4096][256] f32
#define PS      16
#define D       256
#define V       4096
#define M       16384
#define NSPLIT  8               // V / 512 column splits (gemm grid.y)
// Scores packed as u32 keys: q = (u32)((s + 1024) * 512)  (20 bits; s in
// [-1024,1024) with huge slack), key = (q << 12) | col. min() on keys =
// argmin with lowest-index tie-break. Quantum = 1/512.
// fp16 score error sigma ~0.015-0.03; margin 0.25 (= 130 quanta incl. trunc
// slack) covers sum-of-two-errors at >10 sigma; only true-winner exclusion
// events matter (16384 trials) -> P(miss) ~1e-5. Flagged (~3%) get exact fp64.
#define QMARGIN 130

typedef _Float16 half8 __attribute__((ext_vector_type(8)));
typedef _Float16 half4 __attribute__((ext_vector_type(4)));
typedef float    f32x4 __attribute__((ext_vector_type(4)));

__device__ __forceinline__ void gload_lds16(const void* g, void* l) {
  __builtin_amdgcn_global_load_lds(
      (const __attribute__((address_space(1))) unsigned int*)g,
      (__attribute__((address_space(3))) unsigned int*)l, 16, 0, 0);
}

// ---------------------------------------------------------------------------
// Kernel 1: patchify (float4) + fp16 copy of patches for the MFMA GEMM.
// ---------------------------------------------------------------------------
__global__ __launch_bounds__(256) void patchify_half_kernel(
    const float* __restrict__ img, float* __restrict__ outp,
    _Float16* __restrict__ Ah) {
  const int t  = blockIdx.x * 256 + threadIdx.x;   // M*D/4 threads
  const int o4 = t << 2;
  const int b   = o4 >> 16;
  const int rem = o4 & 65535;
  const int n   = rem >> 8;
  const int d   = rem & 255;
  const int py = n >> 4, px = n & 15, i = d >> 4, j = d & 15;
  const float4 v = *(const float4*)(img + (b << 16) + ((py * PS + i) << 8) + px * PS + j);
  *(float4*)(outp + o4) = v;
  half4 h = { (_Float16)v.x, (_Float16)v.y, (_Float16)v.z, (_Float16)v.w };
  *(half4*)(Ah + o4) = h;
}

// ---------------------------------------------------------------------------
// Kernel 2: vocab -> fp16 copy + v2[v] = sum_d vocab[v][d]^2 (one wave / row)
// ---------------------------------------------------------------------------
__global__ __launch_bounds__(256) void vocab_half_v2_kernel(
    const float* __restrict__ vocab, _Float16* __restrict__ Vh,
    float* __restrict__ v2) {
  const int gtid = blockIdx.x * 256 + threadIdx.x;
  const int row  = gtid >> 6;
  const int lane = gtid & 63;
  const float4 v = *(const float4*)(vocab + (size_t)row * D + (lane << 2));
  half4 h = { (_Float16)v.x, (_Float16)v.y, (_Float16)v.z, (_Float16)v.w };
  *(half4*)(Vh + (size_t)row * D + (lane << 2)) = h;
  float s = v.x * v.x + v.y * v.y + v.z * v.z + v.w * v.w;
  #pragma unroll
  for (int off = 32; off > 0; off >>= 1) s += __shfl_down(s, off);
  if (lane == 0) v2[row] = s;
}

// ---------------------------------------------------------------------------
// Kernel 3: fp16 MFMA score GEMM. Block = 128 rows x 512 cols (vt loop of 4
// 128x128 tiles), BK=32, K=256. Running per-row top-2 as packed u32 keys in
// registers across vt; one butterfly per block. Partials [NSPLIT][M].
// ---------------------------------------------------------------------------
__global__ __launch_bounds__(256, 3) void gemm_score_kernel(
    const _Float16* __restrict__ Ah,   // [M][256]
    const _Float16* __restrict__ Vh,   // [V][256]
    const float* __restrict__ v2,
    unsigned* __restrict__ pk1, unsigned* __restrict__ pk2) {
  __shared__ __align__(16) _Float16 As[128 * 32];
  __shared__ __align__(16) _Float16 Bs[128 * 32];
  __shared__ unsigned eK1[128][2];
  __shared__ unsigned eK2[128][2];

  const int tid  = threadIdx.x;
  const int lane = tid & 63;
  const int wid  = tid >> 6;          // 4 waves, 2x2 layout
  const int waveRow = wid >> 1;
  const int waveCol = wid & 1;
  const int row0 = blockIdx.x * 128;
  const int col0 = blockIdx.y * 512;

  // staging: lane -> row (lane>>2), LDS granule (lane&3); fetches global
  // granule (lane&3) ^ ((row>>1)&3) so frag ds_read_b128 is 2-way max (free).
  const int srow  = lane >> 2;
  const int sgran = ((lane & 3) ^ ((lane >> 3) & 3)) << 4;  // byte off in 64B row
  const char* Ag0 = (const char*)(Ah + (size_t)(row0 + wid * 32 + srow) * D) + sgran;
  const char* Bgb = (const char*)(Vh + (size_t)(col0 + wid * 32 + srow) * D) + sgran;
  _Float16* Al0 = As + wid * 32 * 32;
  _Float16* Bl0 = Bs + wid * 32 * 32;

  const int cl = lane & 15;           // fragment row/col within 16
  const int q  = lane >> 4;           // quad: k-chunk selector
  const int fgran = (q ^ ((cl >> 1) & 3)) << 3;  // halves offset in 32-half row

  unsigned kk1[16], kk2[16];
  #pragma unroll
  for (int p = 0; p < 16; ++p) { kk1[p] = 0xFFFFFFFFu; kk2[p] = 0xFFFFFFFFu; }

  for (int vt = 0; vt < 4; ++vt) {
    const char* Bg0 = Bgb + vt * (128 * 512);   // 128 rows x 512 B
    f32x4 acc[4][4];
    #pragma unroll
    for (int i = 0; i < 4; ++i)
      #pragma unroll
      for (int j = 0; j < 4; ++j) acc[i][j] = (f32x4){0.f, 0.f, 0.f, 0.f};

    for (int kt = 0; kt < D / 32; ++kt) {
      const int go = kt * 64;         // bytes along K
      gload_lds16(Ag0 + go,            Al0);
      gload_lds16(Ag0 + 16 * 512 + go, Al0 + 16 * 32);
      gload_lds16(Bg0 + go,            Bl0);
      gload_lds16(Bg0 + 16 * 512 + go, Bl0 + 16 * 32);
      __syncthreads();                // drains vmcnt: tiles resident
      half8 af[4], bf[4];
      #pragma unroll
      for (int f = 0; f < 4; ++f) {
        af[f] = *(const half8*)(As + (waveRow * 64 + f * 16 + cl) * 32 + fgran);
        bf[f] = *(const half8*)(Bs + (waveCol * 64 + f * 16 + cl) * 32 + fgran);
      }
      #pragma unroll
      for (int i = 0; i < 4; ++i)
        #pragma unroll
        for (int j = 0; j < 4; ++j)
          acc[i][j] = __builtin_amdgcn_mfma_f32_16x16x32_f16(af[i], bf[j], acc[i][j], 0, 0, 0);
      __syncthreads();                // LDS reads done before next overwrite
    }

    // fold this 128-col tile into the running packed top-2.
    // C/D layout: col=lane&15, row=quad*4+reg (m89/m91-verified).
    // key_f = (score + 1024)*512 = (v2 + 1024)*512 - 1024*acc
    float Cj[4]; int cidx[4];
    #pragma unroll
    for (int j = 0; j < 4; ++j) {
      const int c = col0 + vt * 128 + waveCol * 64 + j * 16 + cl;
      cidx[j] = c;
      Cj[j] = fmaf(v2[c], 512.0f, 524288.0f);
    }
    #pragma unroll
    for (int i = 0; i < 4; ++i)
      #pragma unroll
      for (int r = 0; r < 4; ++r) {
        const int p = i * 4 + r;
        #pragma unroll
        for (int j = 0; j < 4; ++j) {
          const float kf = fmaf(-1024.0f, acc[i][j][r], Cj[j]);
          const unsigned key = ((unsigned)kf << 12) | (unsigned)cidx[j];
          kk2[p] = min(kk2[p], max(kk1[p], key));
          kk1[p] = min(kk1[p], key);
        }
      }
  }

  // butterfly top-2 merge across the 16 col-holder lanes (within quad group)
  #pragma unroll
  for (int p = 0; p < 16; ++p) {
    unsigned k1 = kk1[p], k2 = kk2[p];
    #pragma unroll
    for (int mask = 1; mask <= 8; mask <<= 1) {
      const unsigned o1 = (unsigned)__shfl_xor((int)k1, mask);
      const unsigned o2 = (unsigned)__shfl_xor((int)k2, mask);
      k2 = min(min(k2, o2), max(k1, o1));
      k1 = min(k1, o1);
    }
    if (cl == 0) {
      const int rl = waveRow * 64 + (p >> 2) * 16 + q * 4 + (p & 3);
      eK1[rl][waveCol] = k1; eK2[rl][waveCol] = k2;
    }
  }
  __syncthreads();
  if (tid < 128) {
    const unsigned a1 = eK1[tid][0], a2 = eK2[tid][0];
    const unsigned b1 = eK1[tid][1], b2 = eK2[tid][1];
    const unsigned m2 = min(min(a2, b2), max(a1, b1));
    const unsigned m1 = min(a1, b1);
    pk1[(size_t)blockIdx.y * M + row0 + tid] = m1;
    pk2[(size_t)blockIdx.y * M + row0 + tid] = m2;
  }
}

// ---------------------------------------------------------------------------
// Kernel 4: merge NSPLIT partials per patch -> token + refine worklist
// ---------------------------------------------------------------------------
__global__ __launch_bounds__(256) void reduce_kernel(
    const unsigned* __restrict__ pk1, const unsigned* __restrict__ pk2,
    float* __restrict__ tok, int* __restrict__ rlist, int* __restrict__ rcount) {
  const int m = blockIdx.x * 256 + threadIdx.x;
  unsigned K1 = 0xFFFFFFFFu, K2 = 0xFFFFFFFFu;
  #pragma unroll
  for (int s = 0; s < NSPLIT; ++s) {
    const unsigned b1 = pk1[(size_t)s * M + m];
    const unsigned b2 = pk2[(size_t)s * M + m];
    K2 = min(min(K2, b2), max(K1, b1));
    K1 = min(K1, b1);
  }
  tok[m] = (float)(K1 & 4095u);
  if ((int)(K2 >> 12) - (int)(K1 >> 12) <= QMARGIN) {
    const int pos = atomicAdd(rcount, 1);
    rlist[pos] = m;
  }
}

// ---------------------------------------------------------------------------
// Kernel 5: exact fp64 rescore of flagged patches over a tiny candidate set.
// Per split: if q2_b <= thresh -> scan its 512 rows (rare); else if
// q1_b <= thresh -> only its winner. One wave per row; per-wave running best
// (no serial LDS scan); 4-way merge at end.
// ---------------------------------------------------------------------------
__global__ __launch_bounds__(256) void refine_kernel(
    const float* __restrict__ patches, const float* __restrict__ vocab,
    const unsigned* __restrict__ pk1, const unsigned* __restrict__ pk2,
    const int* __restrict__ rlist, const int* __restrict__ rcount,
    float* __restrict__ tok) {
  __shared__ float  p[D];
  __shared__ int    rows[V];
  __shared__ int    scan_base[NSPLIT];
  __shared__ int    nrows_s;
  __shared__ double wbest[4];
  __shared__ int    wrow[4];
  const int tid  = threadIdx.x;
  const int lane = tid & 63;
  const int w    = tid >> 6;
  const int n = *rcount;
  for (int e = blockIdx.x; e < n; e += gridDim.x) {
    const int m = rlist[e];
    __syncthreads();                   // protect LDS reuse across entries
    if (tid == 0) nrows_s = 0;
    p[tid] = patches[(size_t)m * D + tid];
    unsigned b1 = 0xFFFFFFFFu, b2 = 0xFFFFFFFFu;
    if (tid < NSPLIT) {
      b1 = pk1[(size_t)tid * M + m];
      b2 = pk2[(size_t)tid * M + m];
    }
    // global q1 across the 8 split partials (wave 0, lanes 0..7)
    unsigned g1 = b1;
    #pragma unroll
    for (int off = 4; off > 0; off >>= 1)
      g1 = min(g1, (unsigned)__shfl_down((int)g1, off));
    const unsigned K1g = (unsigned)__shfl((int)g1, 0);   // valid in wave 0
    __syncthreads();
    if (w == 0 && lane == 0) scan_base[0] = (int)(K1g >> 12);  // stash thresh
    __syncthreads();
    const int thresh_q = scan_base[0] + QMARGIN;
    __syncthreads();
    if (tid < NSPLIT) {
      if ((int)(b2 >> 12) <= thresh_q) {          // split may hide 3rd contender
        const int base = atomicAdd(&nrows_s, 512);
        scan_base[tid] = base;
      } else {
        scan_base[tid] = -1;
        if ((int)(b1 >> 12) <= thresh_q) {        // only stored winner qualifies
          const int pos = atomicAdd(&nrows_s, 1);
          rows[pos] = (int)(b1 & 4095u);
        }
      }
    }
    __syncthreads();
    #pragma unroll
    for (int s = 0; s < NSPLIT; ++s) {
      const int base = scan_base[s];
      if (base >= 0)
        for (int r = tid; r < 512; r += 256) rows[base + r] = s * 512 + r;
    }
    __syncthreads();
    const int nr = nrows_s;
    double best = 1e300;
    int bestrow = 0x7fffffff;
    for (int r = w; r < nr; r += 4) {
      const int row = rows[r];
      const float4 vv = *(const float4*)(vocab + (size_t)row * D + (lane << 2));
      double acc = 0.0, df;
      df = (double)p[(lane << 2) + 0] - (double)vv.x; acc = fma(df, df, acc);
      df = (double)p[(lane << 2) + 1] - (double)vv.y; acc = fma(df, df, acc);
      df = (double)p[(lane << 2) + 2] - (double)vv.z; acc = fma(df, df, acc);
      df = (double)p[(lane << 2) + 3] - (double)vv.w; acc = fma(df, df, acc);
      #pragma unroll
      for (int off = 32; off > 0; off >>= 1) acc += __shfl_down(acc, off);
      if (lane == 0) {
        if (acc < best || (acc == best && row < bestrow)) { best = acc; bestrow = row; }
      }
    }
    if (lane == 0) { wbest[w] = best; wrow[w] = bestrow; }
    __syncthreads();
    if (tid == 0) {
      double fb = wbest[0]; int fr = wrow[0];
      #pragma unroll
      for (int k = 1; k < 4; ++k) {
        if (wbest[k] < fb || (wbest[k] == fb && wrow[k] < fr)) { fb = wbest[k]; fr = wrow[k]; }
      }
      tok[m] = (float)fr;
    }
  }
}

// ---------------------------------------------------------------------------
extern "C" void kernel_launch(void* const* d_in, const int* in_sizes, int n_in,
                              void* d_out, int out_size, void* d_ws, size_t ws_size,
                              hipStream_t stream) {
  const float* images = (const float*)d_in[0];   // [64,256,256]
  const float* vocab  = (const float*)d_in[1];   // [4096,256]
  float* out     = (float*)d_out;
  float* patches = out;            // M*D floats
  float* tokens  = out + (size_t)M * D;

  // workspace layout (bytes):
  // Ah 8MB | Vh 2MB | v2 16KB | pk1 512KB | pk2 512KB | rlist 64KB | rcount
  char* ws = (char*)d_ws;
  _Float16* Ah    = (_Float16*)(ws);
  _Float16* Vh    = (_Float16*)(ws + 8388608);
  float*    v2    = (float*)   (ws + 10485760);
  unsigned* pk1   = (unsigned*)(ws + 10502144);
  unsigned* pk2   = (unsigned*)(ws + 11026432);
  int*      rlist = (int*)     (ws + 11550720);
  int*      rcount= (int*)     (ws + 11616256);

  hipMemsetAsync(rcount, 0, sizeof(int), stream);
  patchify_half_kernel<<<(M * D / 4) / 256, 256, 0, stream>>>(images, patches, Ah);
  vocab_half_v2_kernel<<<(V * 64) / 256, 256, 0, stream>>>(vocab, Vh, v2);
  gemm_score_kernel<<<dim3(M / 128, NSPLIT), 256, 0, stream>>>(Ah, Vh, v2, pk1, pk2);
  reduce_kernel<<<M / 256, 256, 0, stream>>>(pk1, pk2, tokens, rlist, rcount);
  refine_kernel<<<256, 256, 0, stream>>>(patches, vocab, pk1, pk2,
                                         rlist, rcount, tokens);
}

// Round 5
// 222.544 us; speedup vs baseline: 1.3649x; 1.3649x over previous
//
#include <hip/hip_runtime.h>
#include <math.h>

// Problem: images [64,256,256] f32 -> patches [16384][256] f32 (identity perm)
//          tokens [16384] = argmin_v ||patch - vocab[v]||^2, vocab [4096][256] f32
#define PS      16
#define D       256
#define V       4096
#define M       16384
#define NSPLIT  8               // V / 512 column splits (gemm grid.y)
#define PAIR_CAP 2097152
// Scores packed as u32 keys: q = (u32)((s + 1024) * 512)  (20 bits), key =
// (q << 12) | col. min() on keys = argmin with lowest-index tie-break.
// fp16 score error sigma ~0.015-0.03; QMARGIN 130 quanta (=0.254) covers
// sum-of-two-errors at >8 sigma incl. trunc slack. Flagged (~4%) get exact
// fp64 on a candidate set provably containing the true argmin.
#define QMARGIN 130

typedef _Float16 half8 __attribute__((ext_vector_type(8)));
typedef _Float16 half4 __attribute__((ext_vector_type(4)));
typedef float    f32x4 __attribute__((ext_vector_type(4)));

__device__ __forceinline__ void gload_lds16(const void* g, void* l) {
  __builtin_amdgcn_global_load_lds(
      (const __attribute__((address_space(1))) unsigned int*)g,
      (__attribute__((address_space(3))) unsigned int*)l, 16, 0, 0);
}

// ---------------------------------------------------------------------------
// Kernel 1: patchify (float4) + fp16 copy of patches for the MFMA GEMM.
// ---------------------------------------------------------------------------
__global__ __launch_bounds__(256) void patchify_half_kernel(
    const float* __restrict__ img, float* __restrict__ outp,
    _Float16* __restrict__ Ah) {
  const int t  = blockIdx.x * 256 + threadIdx.x;   // M*D/4 threads
  const int o4 = t << 2;
  const int b   = o4 >> 16;
  const int rem = o4 & 65535;
  const int n   = rem >> 8;
  const int d   = rem & 255;
  const int py = n >> 4, px = n & 15, i = d >> 4, j = d & 15;
  const float4 v = *(const float4*)(img + (b << 16) + ((py * PS + i) << 8) + px * PS + j);
  *(float4*)(outp + o4) = v;
  half4 h = { (_Float16)v.x, (_Float16)v.y, (_Float16)v.z, (_Float16)v.w };
  *(half4*)(Ah + o4) = h;
}

// ---------------------------------------------------------------------------
// Kernel 2: vocab -> fp16 copy + v2[v] = sum_d vocab[v][d]^2 (one wave / row)
// ---------------------------------------------------------------------------
__global__ __launch_bounds__(256) void vocab_half_v2_kernel(
    const float* __restrict__ vocab, _Float16* __restrict__ Vh,
    float* __restrict__ v2) {
  const int gtid = blockIdx.x * 256 + threadIdx.x;
  const int row  = gtid >> 6;
  const int lane = gtid & 63;
  const float4 v = *(const float4*)(vocab + (size_t)row * D + (lane << 2));
  half4 h = { (_Float16)v.x, (_Float16)v.y, (_Float16)v.z, (_Float16)v.w };
  *(half4*)(Vh + (size_t)row * D + (lane << 2)) = h;
  float s = v.x * v.x + v.y * v.y + v.z * v.z + v.w * v.w;
  #pragma unroll
  for (int off = 32; off > 0; off >>= 1) s += __shfl_down(s, off);
  if (lane == 0) v2[row] = s;
}

// ---------------------------------------------------------------------------
// Kernel 3: fp16 MFMA score GEMM. Block = 128 rows x 512 cols (vt loop of 4
// 128x128 tiles), BK=32, K=256. Running per-row top-2 as packed u32 keys in
// registers across vt; one butterfly per block. Partials [NSPLIT][M].
// ---------------------------------------------------------------------------
__global__ __launch_bounds__(256, 3) void gemm_score_kernel(
    const _Float16* __restrict__ Ah,   // [M][256]
    const _Float16* __restrict__ Vh,   // [V][256]
    const float* __restrict__ v2,
    unsigned* __restrict__ pk1, unsigned* __restrict__ pk2) {
  __shared__ __align__(16) _Float16 As[128 * 32];
  __shared__ __align__(16) _Float16 Bs[128 * 32];
  __shared__ unsigned eK1[128][2];
  __shared__ unsigned eK2[128][2];

  const int tid  = threadIdx.x;
  const int lane = tid & 63;
  const int wid  = tid >> 6;          // 4 waves, 2x2 layout
  const int waveRow = wid >> 1;
  const int waveCol = wid & 1;
  const int row0 = blockIdx.x * 128;
  const int col0 = blockIdx.y * 512;

  // staging: lane -> row (lane>>2), LDS granule (lane&3); fetches global
  // granule (lane&3) ^ ((row>>1)&3) so frag ds_read_b128 is 2-way max (free).
  const int srow  = lane >> 2;
  const int sgran = ((lane & 3) ^ ((lane >> 3) & 3)) << 4;  // byte off in 64B row
  const char* Ag0 = (const char*)(Ah + (size_t)(row0 + wid * 32 + srow) * D) + sgran;
  const char* Bgb = (const char*)(Vh + (size_t)(col0 + wid * 32 + srow) * D) + sgran;
  _Float16* Al0 = As + wid * 32 * 32;
  _Float16* Bl0 = Bs + wid * 32 * 32;

  const int cl = lane & 15;           // fragment row/col within 16
  const int q  = lane >> 4;           // quad: k-chunk selector
  const int fgran = (q ^ ((cl >> 1) & 3)) << 3;  // halves offset in 32-half row

  unsigned kk1[16], kk2[16];
  #pragma unroll
  for (int p = 0; p < 16; ++p) { kk1[p] = 0xFFFFFFFFu; kk2[p] = 0xFFFFFFFFu; }

  for (int vt = 0; vt < 4; ++vt) {
    const char* Bg0 = Bgb + vt * (128 * 512);   // 128 rows x 512 B
    f32x4 acc[4][4];
    #pragma unroll
    for (int i = 0; i < 4; ++i)
      #pragma unroll
      for (int j = 0; j < 4; ++j) acc[i][j] = (f32x4){0.f, 0.f, 0.f, 0.f};

    for (int kt = 0; kt < D / 32; ++kt) {
      const int go = kt * 64;         // bytes along K
      gload_lds16(Ag0 + go,            Al0);
      gload_lds16(Ag0 + 16 * 512 + go, Al0 + 16 * 32);
      gload_lds16(Bg0 + go,            Bl0);
      gload_lds16(Bg0 + 16 * 512 + go, Bl0 + 16 * 32);
      __syncthreads();                // drains vmcnt: tiles resident
      half8 af[4], bf[4];
      #pragma unroll
      for (int f = 0; f < 4; ++f) {
        af[f] = *(const half8*)(As + (waveRow * 64 + f * 16 + cl) * 32 + fgran);
        bf[f] = *(const half8*)(Bs + (waveCol * 64 + f * 16 + cl) * 32 + fgran);
      }
      #pragma unroll
      for (int i = 0; i < 4; ++i)
        #pragma unroll
        for (int j = 0; j < 4; ++j)
          acc[i][j] = __builtin_amdgcn_mfma_f32_16x16x32_f16(af[i], bf[j], acc[i][j], 0, 0, 0);
      __syncthreads();                // LDS reads done before next overwrite
    }

    // fold this 128-col tile into the running packed top-2.
    // C/D layout: col=lane&15, row=quad*4+reg (m89/m91-verified).
    // key_f = (score + 1024)*512 = (v2 + 1024)*512 - 1024*acc
    float Cj[4]; int cidx[4];
    #pragma unroll
    for (int j = 0; j < 4; ++j) {
      const int c = col0 + vt * 128 + waveCol * 64 + j * 16 + cl;
      cidx[j] = c;
      Cj[j] = fmaf(v2[c], 512.0f, 524288.0f);
    }
    #pragma unroll
    for (int i = 0; i < 4; ++i)
      #pragma unroll
      for (int r = 0; r < 4; ++r) {
        const int p = i * 4 + r;
        #pragma unroll
        for (int j = 0; j < 4; ++j) {
          const float kf = fmaf(-1024.0f, acc[i][j][r], Cj[j]);
          const unsigned key = ((unsigned)kf << 12) | (unsigned)cidx[j];
          kk2[p] = min(kk2[p], max(kk1[p], key));
          kk1[p] = min(kk1[p], key);
        }
      }
  }

  // butterfly top-2 merge across the 16 col-holder lanes (within quad group)
  #pragma unroll
  for (int p = 0; p < 16; ++p) {
    unsigned k1 = kk1[p], k2 = kk2[p];
    #pragma unroll
    for (int mask = 1; mask <= 8; mask <<= 1) {
      const unsigned o1 = (unsigned)__shfl_xor((int)k1, mask);
      const unsigned o2 = (unsigned)__shfl_xor((int)k2, mask);
      k2 = min(min(k2, o2), max(k1, o1));
      k1 = min(k1, o1);
    }
    if (cl == 0) {
      const int rl = waveRow * 64 + (p >> 2) * 16 + q * 4 + (p & 3);
      eK1[rl][waveCol] = k1; eK2[rl][waveCol] = k2;
    }
  }
  __syncthreads();
  if (tid < 128) {
    const unsigned a1 = eK1[tid][0], a2 = eK2[tid][0];
    const unsigned b1 = eK1[tid][1], b2 = eK2[tid][1];
    const unsigned m2 = min(min(a2, b2), max(a1, b1));
    const unsigned m1 = min(a1, b1);
    pk1[(size_t)blockIdx.y * M + row0 + tid] = m1;
    pk2[(size_t)blockIdx.y * M + row0 + tid] = m2;
  }
}

// ---------------------------------------------------------------------------
// Kernel 4: merge NSPLIT partials per patch -> token + refine worklist;
// also inits minbits/tokidx for the refine passes.
// ---------------------------------------------------------------------------
__global__ __launch_bounds__(256) void reduce_kernel(
    const unsigned* __restrict__ pk1, const unsigned* __restrict__ pk2,
    float* __restrict__ tok, int* __restrict__ rlist, int* __restrict__ rcount,
    unsigned long long* __restrict__ minbits, int* __restrict__ tokidx) {
  const int m = blockIdx.x * 256 + threadIdx.x;
  unsigned K1 = 0xFFFFFFFFu, K2 = 0xFFFFFFFFu;
  #pragma unroll
  for (int s = 0; s < NSPLIT; ++s) {
    const unsigned b1 = pk1[(size_t)s * M + m];
    const unsigned b2 = pk2[(size_t)s * M + m];
    K2 = min(min(K2, b2), max(K1, b1));
    K1 = min(K1, b1);
  }
  tok[m] = (float)(K1 & 4095u);
  minbits[m] = 0xFFFFFFFFFFFFFFFFull;
  tokidx[m]  = 0x7FFFFFFF;
  if ((int)(K2 >> 12) - (int)(K1 >> 12) <= QMARGIN) {
    const int pos = atomicAdd(rcount, 1);
    rlist[pos] = m;
  }
}

// ---------------------------------------------------------------------------
// Kernel 5: gather candidate (patch,row) pairs for flagged patches.
// Per split: if q2_b <= thresh -> expand its 512 rows; else if q1_b <= thresh
// -> just its stored winner. Pairs packed (m<<12)|row.
// ---------------------------------------------------------------------------
__global__ __launch_bounds__(256) void refine_gather(
    const unsigned* __restrict__ pk1, const unsigned* __restrict__ pk2,
    const int* __restrict__ rlist, const int* __restrict__ rcount,
    unsigned* __restrict__ pairs, int* __restrict__ paircount) {
  __shared__ int hoff[NSPLIT];
  __shared__ int loff[NSPLIT];
  __shared__ unsigned lwin[NSPLIT];
  __shared__ int lcount_s, gbase_s, thq_s;
  const int tid = threadIdx.x;
  const int n = *rcount;
  for (int e = blockIdx.x; e < n; e += gridDim.x) {
    const int m = rlist[e];
    __syncthreads();                   // protect LDS reuse across entries
    if (tid == 0) lcount_s = 0;
    unsigned b1 = 0xFFFFFFFFu, b2 = 0xFFFFFFFFu;
    if (tid < NSPLIT) {
      b1 = pk1[(size_t)tid * M + m];
      b2 = pk2[(size_t)tid * M + m];
    }
    unsigned g1 = b1;                  // min over lanes 0..7 (wave 0)
    #pragma unroll
    for (int off = 4; off > 0; off >>= 1)
      g1 = min(g1, (unsigned)__shfl_down((int)g1, off));
    if (tid == 0) thq_s = (int)(g1 >> 12) + QMARGIN;
    __syncthreads();
    const int th = thq_s;
    if (tid < NSPLIT) {
      const bool heavy = ((int)(b2 >> 12) <= th);
      const bool light = !heavy && ((int)(b1 >> 12) <= th);
      const int cnt = heavy ? 512 : (light ? 1 : 0);
      const int o = cnt ? atomicAdd(&lcount_s, cnt) : 0;
      hoff[tid] = heavy ? o : -1;
      loff[tid] = light ? o : -1;
      lwin[tid] = b1;
    }
    __syncthreads();
    if (tid == 0) {
      int base = atomicAdd(paircount, lcount_s);
      if (base + lcount_s > PAIR_CAP) base = -1;  // overflow guard (never hit)
      gbase_s = base;
    }
    __syncthreads();
    const int gbase = gbase_s;
    if (gbase >= 0) {
      if (tid < NSPLIT && loff[tid] >= 0)
        pairs[gbase + loff[tid]] = ((unsigned)m << 12) | (lwin[tid] & 4095u);
      #pragma unroll
      for (int s = 0; s < NSPLIT; ++s) {
        if (hoff[s] >= 0)
          for (int r = tid; r < 512; r += 256)
            pairs[gbase + hoff[s] + r] = ((unsigned)m << 12) | (unsigned)(s * 512 + r);
      }
    }
  }
}

// ---------------------------------------------------------------------------
// Kernel 6: score pairs, one wave per pair, exact fp64.
// pass 0: atomicMin(minbits[m], bits(d2))  (positive doubles order as u64)
// pass 1: bits(d2)==minbits[m] -> atomicMin(tokidx[m], row)  (index tie-break)
// ---------------------------------------------------------------------------
__global__ __launch_bounds__(256) void refine_score(
    const float* __restrict__ patches, const float* __restrict__ vocab,
    const unsigned* __restrict__ pairs, const int* __restrict__ paircount,
    unsigned long long* __restrict__ minbits, int* __restrict__ tokidx,
    int pass) {
  const int lane = threadIdx.x & 63;
  const int gw = (blockIdx.x * 256 + threadIdx.x) >> 6;
  const int nw = (gridDim.x * 256) >> 6;
  int np = *paircount;
  if (np > PAIR_CAP) np = PAIR_CAP;
  for (int i = gw; i < np; i += nw) {
    const unsigned pr = pairs[i];
    const int m = pr >> 12, row = pr & 4095;
    const float4 pv = *(const float4*)(patches + (size_t)m * D + (lane << 2));
    const float4 vv = *(const float4*)(vocab + (size_t)row * D + (lane << 2));
    double acc = 0.0, df;
    df = (double)pv.x - (double)vv.x; acc = fma(df, df, acc);
    df = (double)pv.y - (double)vv.y; acc = fma(df, df, acc);
    df = (double)pv.z - (double)vv.z; acc = fma(df, df, acc);
    df = (double)pv.w - (double)vv.w; acc = fma(df, df, acc);
    #pragma unroll
    for (int off = 32; off > 0; off >>= 1) acc += __shfl_down(acc, off);
    if (lane == 0) {
      const unsigned long long bits = (unsigned long long)__double_as_longlong(acc);
      if (pass == 0) atomicMin(&minbits[m], bits);
      else if (bits == minbits[m]) atomicMin(&tokidx[m], row);
    }
  }
}

// ---------------------------------------------------------------------------
// Kernel 7: write refined tokens back
// ---------------------------------------------------------------------------
__global__ __launch_bounds__(256) void refine_final(
    const int* __restrict__ rlist, const int* __restrict__ rcount,
    const int* __restrict__ tokidx, float* __restrict__ tok) {
  const int n = *rcount;
  for (int e = blockIdx.x * 256 + threadIdx.x; e < n; e += gridDim.x * 256) {
    const int m = rlist[e];
    tok[m] = (float)tokidx[m];
  }
}

// ---------------------------------------------------------------------------
extern "C" void kernel_launch(void* const* d_in, const int* in_sizes, int n_in,
                              void* d_out, int out_size, void* d_ws, size_t ws_size,
                              hipStream_t stream) {
  const float* images = (const float*)d_in[0];   // [64,256,256]
  const float* vocab  = (const float*)d_in[1];   // [4096,256]
  float* out     = (float*)d_out;
  float* patches = out;            // M*D floats
  float* tokens  = out + (size_t)M * D;

  // workspace layout (bytes):
  // Ah 8MB | Vh 2MB | v2 16KB | pk1 512KB | pk2 512KB | rlist 64KB |
  // rcount/paircount 128B | minbits 128KB | tokidx 64KB | pairs 8MB  (~19.3MB)
  char* ws = (char*)d_ws;
  _Float16* Ah       = (_Float16*)(ws);
  _Float16* Vh       = (_Float16*)(ws + 8388608);
  float*    v2       = (float*)   (ws + 10485760);
  unsigned* pk1      = (unsigned*)(ws + 10502144);
  unsigned* pk2      = (unsigned*)(ws + 11026432);
  int*      rlist    = (int*)     (ws + 11550720);
  int*      rcount   = (int*)     (ws + 11616256);
  int*      paircount= (int*)     (ws + 11616320);
  unsigned long long* minbits = (unsigned long long*)(ws + 11616384);
  int*      tokidx   = (int*)     (ws + 11747456);
  unsigned* pairs    = (unsigned*)(ws + 11812992);

  hipMemsetAsync(rcount, 0, 128, stream);   // rcount + paircount
  patchify_half_kernel<<<(M * D / 4) / 256, 256, 0, stream>>>(images, patches, Ah);
  vocab_half_v2_kernel<<<(V * 64) / 256, 256, 0, stream>>>(vocab, Vh, v2);
  gemm_score_kernel<<<dim3(M / 128, NSPLIT), 256, 0, stream>>>(Ah, Vh, v2, pk1, pk2);
  reduce_kernel<<<M / 256, 256, 0, stream>>>(pk1, pk2, tokens, rlist, rcount,
                                             minbits, tokidx);
  refine_gather<<<256, 256, 0, stream>>>(pk1, pk2, rlist, rcount, pairs, paircount);
  refine_score<<<512, 256, 0, stream>>>(patches, vocab, pairs, paircount,
                                        minbits, tokidx, 0);
  refine_score<<<512, 256, 0, stream>>>(patches, vocab, pairs, paircount,
                                        minbits, tokidx, 1);
  refine_final<<<16, 256, 0, stream>>>(rlist, rcount, tokidx, tokens);
}